// Round 1
// baseline (218.535 us; speedup 1.0000x reference)
//
#include <hip/hip_runtime.h>
#include <math.h>

// GATModelWithAttention — the cross-attention has key-seq-len 1, so
// softmax == 1.0 exactly and ctx == V. The entire GAT/pooling/Q/K branch is
// dead code. The model reduces to a per-row MLP on biobert_cls:
//   V   = bio @ ca_wv + ca_bv                  [256,256]
//   ctx = LN(V @ ca_wo + ca_bo; ca_ln)         [256,256]
//   ffn = relu(ctx @ w1 + b1) @ w2 + b2        [256,256]
//   out = LN(ctx + ffn; fn)                    [256,256]
//   logits = out @ fc_w + fc_b                 [256,5]

// Block-wide mean/rstd over 256 values (one per thread). s = 8-float scratch.
__device__ __forceinline__ void block_stats(float x, float& m, float& rs, float* s) {
    float sum = x, sq = x * x;
    #pragma unroll
    for (int o = 32; o > 0; o >>= 1) {
        sum += __shfl_down(sum, o);
        sq  += __shfl_down(sq,  o);
    }
    const int lane = threadIdx.x & 63;
    const int wid  = threadIdx.x >> 6;
    if (lane == 0) { s[wid] = sum; s[4 + wid] = sq; }
    __syncthreads();
    if (threadIdx.x == 0) {
        float S = s[0] + s[1] + s[2] + s[3];
        float Q = s[4] + s[5] + s[6] + s[7];
        float mm = S * (1.0f / 256.0f);
        float var = Q * (1.0f / 256.0f) - mm * mm;   // biased var, matches jnp.var
        s[0] = mm;
        s[1] = rsqrtf(fmaxf(var, 0.0f) + 1e-5f);
    }
    __syncthreads();
    m  = s[0];
    rs = s[1];
    __syncthreads();   // protect s before next reuse
}

__global__ __launch_bounds__(256)
void gat_head_kernel(const float* __restrict__ bio,   // [256,768]
                     const float* __restrict__ wv, const float* __restrict__ bv,
                     const float* __restrict__ wo, const float* __restrict__ bo,
                     const float* __restrict__ lng, const float* __restrict__ lnb,
                     const float* __restrict__ w1, const float* __restrict__ b1,
                     const float* __restrict__ w2, const float* __restrict__ b2,
                     const float* __restrict__ fng, const float* __restrict__ fnb,
                     const float* __restrict__ fcw, const float* __restrict__ fcb,
                     float* __restrict__ out)         // [256,5]
{
    const int b = blockIdx.x;
    const int j = threadIdx.x;    // channel 0..255

    __shared__ float s_bio[768];
    __shared__ float s_vec[256];  // V, then u, then final 'out' row
    __shared__ float s_ctx[256];
    __shared__ float s_red[8];

    // stage biobert row
    #pragma unroll
    for (int i = j; i < 768; i += 256) s_bio[i] = bio[b * 768 + i];
    __syncthreads();

    // V = bio @ wv + bv   (wv column j, coalesced across threads)
    float v = bv[j];
    #pragma unroll 8
    for (int i = 0; i < 768; ++i) v = fmaf(s_bio[i], wv[i * 256 + j], v);
    s_vec[j] = v;
    __syncthreads();

    // t = V @ wo + bo
    float t = bo[j];
    #pragma unroll 8
    for (int i = 0; i < 256; ++i) t = fmaf(s_vec[i], wo[i * 256 + j], t);

    float m, rs;
    block_stats(t, m, rs, s_red);
    const float ctx = (t - m) * rs * lng[j] + lnb[j];
    s_ctx[j] = ctx;
    __syncthreads();

    // u = relu(ctx @ w1 + b1)
    float u = b1[j];
    #pragma unroll 8
    for (int i = 0; i < 256; ++i) u = fmaf(s_ctx[i], w1[i * 256 + j], u);
    u = fmaxf(u, 0.0f);
    s_vec[j] = u;     // s_vec's previous value (V) last read before block_stats barriers
    __syncthreads();

    // f = u @ w2 + b2 ; o = ctx + f
    float f = b2[j];
    #pragma unroll 8
    for (int i = 0; i < 256; ++i) f = fmaf(s_vec[i], w2[i * 256 + j], f);
    const float o = ctx + f;

    block_stats(o, m, rs, s_red);
    const float oj = (o - m) * rs * fng[j] + fnb[j];
    s_vec[j] = oj;    // safe: last s_vec read was before block_stats barriers
    __syncthreads();

    // logits = out_row @ fc_w + fc_b   (fc_w is [256,5] row-major)
    if (j < 5) {
        float acc = fcb[j];
        #pragma unroll 8
        for (int i = 0; i < 256; ++i) acc = fmaf(s_vec[i], fcw[i * 5 + j], acc);
        out[b * 5 + j] = acc;
    }
}

extern "C" void kernel_launch(void* const* d_in, const int* in_sizes, int n_in,
                              void* d_out, int out_size, void* d_ws, size_t ws_size,
                              hipStream_t stream) {
    // setup_inputs() order:
    //  0:x 1:biobert_cls
    //  2..9   g1_wl,g1_bl,g1_wr,g1_br,g1_att,g1_bias,bn1_g,bn1_b
    // 10..17  g2_*   18..25 g3_*
    // 26:ca_wq 27:ca_bq 28:ca_wk 29:ca_bk 30:ca_wv 31:ca_bv
    // 32:ca_wo 33:ca_bo 34:ca_ln_g 35:ca_ln_b
    // 36:ffn_w1 37:ffn_b1 38:ffn_w2 39:ffn_b2
    // 40:fc_w 41:fc_b 42:fn_g 43:fn_b
    // 44:edge_src 45:edge_dst 46:batch
    const float* bio = (const float*)d_in[1];
    const float* wv  = (const float*)d_in[30];
    const float* bv  = (const float*)d_in[31];
    const float* wo  = (const float*)d_in[32];
    const float* bo  = (const float*)d_in[33];
    const float* lng = (const float*)d_in[34];
    const float* lnb = (const float*)d_in[35];
    const float* w1  = (const float*)d_in[36];
    const float* b1  = (const float*)d_in[37];
    const float* w2  = (const float*)d_in[38];
    const float* b2  = (const float*)d_in[39];
    const float* fcw = (const float*)d_in[40];
    const float* fcb = (const float*)d_in[41];
    const float* fng = (const float*)d_in[42];
    const float* fnb = (const float*)d_in[43];
    float* out = (float*)d_out;

    hipLaunchKernelGGL(gat_head_kernel, dim3(256), dim3(256), 0, stream,
                       bio, wv, bv, wo, bo, lng, lnb,
                       w1, b1, w2, b2, fng, fnb, fcw, fcb, out);
}

// Round 2
// 180.367 us; speedup vs baseline: 1.2116x; 1.2116x over previous
//
#include <hip/hip_runtime.h>
#include <math.h>

// Model collapses (softmax over length-1 key axis == 1.0 => ctx == V) to a
// per-row MLP on biobert_cls [256,768]:
//   V   = bio @ ca_wv + ca_bv                  [256,256]
//   ctx = LN(V @ ca_wo + ca_bo; ca_ln)
//   ffn = relu(ctx @ w1 + b1) @ w2 + b2
//   out = LN(ctx + ffn; fn)
//   logits = out @ fc_w + fc_b                 [256,5]
//
// R2 layout: 128 blocks x 1024 threads. Each block owns 2 rows (register-level
// weight reuse: 1 load -> 2 FMAs). Threads: q = tid>>8 is the 4-way K-split
// group (q<2 also "owns" row q for reductions/LN), j = tid&255 is the output
// channel. Partial sums exchanged via LDS.

// Per-group (256-thread) mean/rstd over channel j. All 1024 threads must call
// (uniform barriers); only q<2 results are meaningful.
__device__ __forceinline__ void group_stats(float x, int q, int j,
                                            float (*sred)[8], float& m, float& rs) {
    float sum = x, sq = x * x;
    #pragma unroll
    for (int o = 32; o > 0; o >>= 1) {
        sum += __shfl_down(sum, o);
        sq  += __shfl_down(sq,  o);
    }
    const int lane = j & 63;
    const int w    = j >> 6;          // wave id within the 256-thread group
    if (lane == 0) { sred[q][w] = sum; sred[q][4 + w] = sq; }
    __syncthreads();
    if (j == 0) {                     // one thread per group
        float S = sred[q][0] + sred[q][1] + sred[q][2] + sred[q][3];
        float Q = sred[q][4] + sred[q][5] + sred[q][6] + sred[q][7];
        float mm  = S * (1.0f / 256.0f);
        float var = Q * (1.0f / 256.0f) - mm * mm;   // biased var (jnp.var)
        sred[q][0] = mm;
        sred[q][1] = rsqrtf(fmaxf(var, 0.0f) + 1e-5f);
    }
    __syncthreads();
    m  = sred[q][0];
    rs = sred[q][1];
    __syncthreads();                  // protect sred before reuse
}

__global__ __launch_bounds__(1024)
void gat_head_kernel(const float* __restrict__ bio,   // [256,768]
                     const float* __restrict__ wv, const float* __restrict__ bv,
                     const float* __restrict__ wo, const float* __restrict__ bo,
                     const float* __restrict__ lng, const float* __restrict__ lnb,
                     const float* __restrict__ w1, const float* __restrict__ b1,
                     const float* __restrict__ w2, const float* __restrict__ b2,
                     const float* __restrict__ fng, const float* __restrict__ fnb,
                     const float* __restrict__ fcw, const float* __restrict__ fcb,
                     float* __restrict__ out)         // [256,5]
{
    const int b   = blockIdx.x;       // rows 2b, 2b+1
    const int tid = threadIdx.x;
    const int q   = tid >> 8;         // K-split group 0..3; q<2 owns row q
    const int j   = tid & 255;        // output channel

    __shared__ float s_bio[2][768];
    __shared__ float s_a[2][256];     // current staged activation rows
    __shared__ float s_part[4][2][256];
    __shared__ float s_red[4][8];

    // stage both biobert rows (1536 contiguous floats)
    for (int i = tid; i < 1536; i += 1024)
        ((float*)s_bio)[i] = bio[b * 1536 + i];
    __syncthreads();

    // ---- V = bio @ wv + bv  (K=768, 4-way split: 192 per group) ----
    {
        float a0 = 0.f, a1 = 0.f;
        const float* wp = wv + (q * 192) * 256 + j;
        const float* x0 = &s_bio[0][q * 192];
        const float* x1 = &s_bio[1][q * 192];
        #pragma unroll 8
        for (int k = 0; k < 192; ++k) {
            float w = wp[k * 256];
            a0 = fmaf(x0[k], w, a0);
            a1 = fmaf(x1[k], w, a1);
        }
        s_part[q][0][j] = a0;
        s_part[q][1][j] = a1;
    }
    __syncthreads();
    if (q < 2)
        s_a[q][j] = s_part[0][q][j] + s_part[1][q][j]
                  + s_part[2][q][j] + s_part[3][q][j] + bv[j];
    __syncthreads();

    // helper pattern for K=256 GEMM partials (64 per group), 2 rows
    #define GEMM256(W)                                                  \
    {                                                                   \
        float a0 = 0.f, a1 = 0.f;                                       \
        const float* wp = (W) + (q * 64) * 256 + j;                     \
        const float* x0 = &s_a[0][q * 64];                              \
        const float* x1 = &s_a[1][q * 64];                              \
        _Pragma("unroll 8")                                             \
        for (int k = 0; k < 64; ++k) {                                  \
            float w = wp[k * 256];                                      \
            a0 = fmaf(x0[k], w, a0);                                    \
            a1 = fmaf(x1[k], w, a1);                                    \
        }                                                               \
        s_part[q][0][j] = a0;                                           \
        s_part[q][1][j] = a1;                                           \
    }                                                                   \
    __syncthreads();

    // ---- t = V @ wo + bo ; ctx = LN(t) ----
    GEMM256(wo);
    float t = 0.f;
    if (q < 2)
        t = s_part[0][q][j] + s_part[1][q][j]
          + s_part[2][q][j] + s_part[3][q][j] + bo[j];
    float m, rs;
    group_stats(t, q, j, s_red, m, rs);
    const float ctx = (q < 2) ? (t - m) * rs * lng[j] + lnb[j] : 0.f;
    if (q < 2) s_a[q][j] = ctx;       // V no longer needed
    __syncthreads();

    // ---- u = relu(ctx @ w1 + b1) ----
    GEMM256(w1);
    if (q < 2) {
        float u = s_part[0][q][j] + s_part[1][q][j]
                + s_part[2][q][j] + s_part[3][q][j] + b1[j];
        s_a[q][j] = fmaxf(u, 0.0f);
    }
    __syncthreads();

    // ---- f = u @ w2 + b2 ; o = LN(ctx + f) ----
    GEMM256(w2);
    float o = 0.f;
    if (q < 2)
        o = s_part[0][q][j] + s_part[1][q][j]
          + s_part[2][q][j] + s_part[3][q][j] + b2[j] + ctx;
    group_stats(o, q, j, s_red, m, rs);
    if (q < 2) s_a[q][j] = (o - m) * rs * fng[j] + fnb[j];
    __syncthreads();

    // ---- logits = out_row @ fc_w + fc_b  (fc_w is [256,5]) ----
    if (q < 2 && j < 5) {
        float acc = fcb[j];
        #pragma unroll 8
        for (int i = 0; i < 256; ++i)
            acc = fmaf(s_a[q][i], fcw[i * 5 + j], acc);
        out[(2 * b + q) * 5 + j] = acc;
    }
    #undef GEMM256
}

extern "C" void kernel_launch(void* const* d_in, const int* in_sizes, int n_in,
                              void* d_out, int out_size, void* d_ws, size_t ws_size,
                              hipStream_t stream) {
    // input order: 0:x 1:biobert_cls 2..25 gat/bn params (dead)
    // 26:ca_wq 27:ca_bq 28:ca_wk 29:ca_bk 30:ca_wv 31:ca_bv 32:ca_wo 33:ca_bo
    // 34:ca_ln_g 35:ca_ln_b 36:ffn_w1 37:ffn_b1 38:ffn_w2 39:ffn_b2
    // 40:fc_w 41:fc_b 42:fn_g 43:fn_b 44:edge_src 45:edge_dst 46:batch
    const float* bio = (const float*)d_in[1];
    const float* wv  = (const float*)d_in[30];
    const float* bv  = (const float*)d_in[31];
    const float* wo  = (const float*)d_in[32];
    const float* bo  = (const float*)d_in[33];
    const float* lng = (const float*)d_in[34];
    const float* lnb = (const float*)d_in[35];
    const float* w1  = (const float*)d_in[36];
    const float* b1  = (const float*)d_in[37];
    const float* w2  = (const float*)d_in[38];
    const float* b2  = (const float*)d_in[39];
    const float* fcw = (const float*)d_in[40];
    const float* fcb = (const float*)d_in[41];
    const float* fng = (const float*)d_in[42];
    const float* fnb = (const float*)d_in[43];
    float* out = (float*)d_out;

    hipLaunchKernelGGL(gat_head_kernel, dim3(128), dim3(1024), 0, stream,
                       bio, wv, bv, wo, bo, lng, lnb,
                       w1, b1, w2, b2, fng, fnb, fcw, fcb, out);
}

// Round 3
// 168.126 us; speedup vs baseline: 1.2998x; 1.0728x over previous
//
#include <hip/hip_runtime.h>
#include <math.h>

// Model collapses (softmax over a length-1 key axis == 1.0 => ctx == V) to a
// per-row MLP on biobert_cls [256,768]:
//   V      = bio @ ca_wv + ca_bv                 [256,256]
//   ctx    = LN(V @ ca_wo + ca_bo; ca_ln)
//   ffn    = relu(ctx @ w1 + b1) @ w2 + b2
//   outr   = LN(ctx + ffn; fn)
//   logits = outr @ fc_w + fc_b                  [256,5]
//
// R3: 256 blocks (1 row/block, all CUs busy) x 512 threads (8 waves).
//   jq = tid&63  -> channel quad (float4 weight loads, 4 FMAs per 16B fetch)
//   q  = tid>>6  -> 8-way K-split group (== wave id; activation reads are
//                   wave-uniform LDS broadcasts)
// Partials meet in LDS; LN via shuffle+LDS block reduction.

// Block-wide LN stats over 256 values held by threads tid<256 (x==0 for
// tid>=256). All 512 threads must call (uniform barriers).
__device__ __forceinline__ void ln_stats(float x, int tid, float* sred,
                                         float& m, float& rs) {
    float sum = x, sq = x * x;
    #pragma unroll
    for (int o = 32; o > 0; o >>= 1) {
        sum += __shfl_down(sum, o);
        sq  += __shfl_down(sq,  o);
    }
    const int lane = tid & 63, w = tid >> 6;      // 8 waves
    if (lane == 0) { sred[w] = sum; sred[8 + w] = sq; }
    __syncthreads();
    if (tid == 0) {
        float S = 0.f, Q = 0.f;
        #pragma unroll
        for (int g = 0; g < 8; ++g) { S += sred[g]; Q += sred[8 + g]; }
        float mm  = S * (1.0f / 256.0f);
        float var = Q * (1.0f / 256.0f) - mm * mm;   // biased var (jnp.var)
        sred[0] = mm;
        sred[1] = rsqrtf(fmaxf(var, 0.0f) + 1e-5f);
    }
    __syncthreads();
    m  = sred[0];
    rs = sred[1];
    __syncthreads();                               // protect sred before reuse
}

__global__ __launch_bounds__(512)
void mlp_head_kernel(const float* __restrict__ bio,   // [256,768]
                     const float* __restrict__ wv, const float* __restrict__ bv,
                     const float* __restrict__ wo, const float* __restrict__ bo,
                     const float* __restrict__ lng, const float* __restrict__ lnb,
                     const float* __restrict__ w1, const float* __restrict__ b1,
                     const float* __restrict__ w2, const float* __restrict__ b2,
                     const float* __restrict__ fng, const float* __restrict__ fnb,
                     const float* __restrict__ fcw, const float* __restrict__ fcb,
                     float* __restrict__ out)         // [256,5]
{
    const int b   = blockIdx.x;     // row
    const int tid = threadIdx.x;
    const int q   = tid >> 6;       // K-group 0..7 (wave id)
    const int jq  = tid & 63;       // channel quad: channels 4*jq..4*jq+3

    __shared__ float s_bio[768];
    __shared__ float s_act[256];
    __shared__ float s_part[8][256];
    __shared__ float s_red[16];

    for (int i = tid; i < 768; i += 512) s_bio[i] = bio[b * 768 + i];
    __syncthreads();

    // ---- V = bio @ wv + bv  (K=768, 8 x 96) ----
    {
        float4 acc = {0.f, 0.f, 0.f, 0.f};
        const float4* wp = (const float4*)wv + (q * 96) * 64 + jq;
        const float*  x  = &s_bio[q * 96];
        #pragma unroll 16
        for (int k = 0; k < 96; ++k) {
            float4 w = wp[k * 64];
            float xv = x[k];
            acc.x = fmaf(xv, w.x, acc.x);
            acc.y = fmaf(xv, w.y, acc.y);
            acc.z = fmaf(xv, w.z, acc.z);
            acc.w = fmaf(xv, w.w, acc.w);
        }
        ((float4*)s_part[q])[jq] = acc;
    }
    __syncthreads();
    if (tid < 256) {
        float v = bv[tid];
        #pragma unroll
        for (int g = 0; g < 8; ++g) v += s_part[g][tid];
        s_act[tid] = v;
    }
    __syncthreads();

    // K=256 GEMM partials (8 x 32), float4 channels
    #define GEMM256(W)                                                  \
    {                                                                   \
        float4 acc = {0.f, 0.f, 0.f, 0.f};                              \
        const float4* wp = (const float4*)(W) + (q * 32) * 64 + jq;     \
        const float*  x  = &s_act[q * 32];                              \
        _Pragma("unroll 16")                                            \
        for (int k = 0; k < 32; ++k) {                                  \
            float4 w = wp[k * 64];                                      \
            float xv = x[k];                                            \
            acc.x = fmaf(xv, w.x, acc.x);                               \
            acc.y = fmaf(xv, w.y, acc.y);                               \
            acc.z = fmaf(xv, w.z, acc.z);                               \
            acc.w = fmaf(xv, w.w, acc.w);                               \
        }                                                               \
        ((float4*)s_part[q])[jq] = acc;                                 \
    }                                                                   \
    __syncthreads();

    // ---- t = V @ wo + bo ; ctx = LN(t) ----
    GEMM256(wo);
    float t = 0.f;
    if (tid < 256) {
        t = bo[tid];
        #pragma unroll
        for (int g = 0; g < 8; ++g) t += s_part[g][tid];
    }
    float m, rs;
    ln_stats(tid < 256 ? t : 0.f, tid, s_red, m, rs);
    float ctx = 0.f;                 // kept in-register for the residual
    if (tid < 256) {
        ctx = (t - m) * rs * lng[tid] + lnb[tid];
        s_act[tid] = ctx;
    }
    __syncthreads();

    // ---- u = relu(ctx @ w1 + b1) ----
    GEMM256(w1);
    if (tid < 256) {
        float u = b1[tid];
        #pragma unroll
        for (int g = 0; g < 8; ++g) u += s_part[g][tid];
        s_act[tid] = fmaxf(u, 0.0f);
    }
    __syncthreads();

    // ---- f = u @ w2 + b2 ; o = LN(ctx + f) ----
    GEMM256(w2);
    float o = 0.f;
    if (tid < 256) {
        o = b2[tid] + ctx;
        #pragma unroll
        for (int g = 0; g < 8; ++g) o += s_part[g][tid];
    }
    ln_stats(tid < 256 ? o : 0.f, tid, s_red, m, rs);
    if (tid < 256) s_act[tid] = (o - m) * rs * fng[tid] + fnb[tid];
    __syncthreads();

    // ---- logits = outr @ fc_w + fc_b  (fc_w is [256,5]) ----
    // wave w (w<5) computes class w: lane l sums k = l, l+64, l+128, l+192.
    if (q < 5) {
        float acc = 0.f;
        #pragma unroll
        for (int e = 0; e < 4; ++e) {
            int k = jq + 64 * e;
            acc = fmaf(s_act[k], fcw[k * 5 + q], acc);
        }
        #pragma unroll
        for (int o2 = 32; o2 > 0; o2 >>= 1) acc += __shfl_down(acc, o2);
        if (jq == 0) out[b * 5 + q] = acc + fcb[q];
    }
    #undef GEMM256
}

extern "C" void kernel_launch(void* const* d_in, const int* in_sizes, int n_in,
                              void* d_out, int out_size, void* d_ws, size_t ws_size,
                              hipStream_t stream) {
    // input order: 0:x 1:biobert_cls 2..25 gat/bn params (dead)
    // 26:ca_wq 27:ca_bq 28:ca_wk 29:ca_bk 30:ca_wv 31:ca_bv 32:ca_wo 33:ca_bo
    // 34:ca_ln_g 35:ca_ln_b 36:ffn_w1 37:ffn_b1 38:ffn_w2 39:ffn_b2
    // 40:fc_w 41:fc_b 42:fn_g 43:fn_b 44:edge_src 45:edge_dst 46:batch
    const float* bio = (const float*)d_in[1];
    const float* wv  = (const float*)d_in[30];
    const float* bv  = (const float*)d_in[31];
    const float* wo  = (const float*)d_in[32];
    const float* bo  = (const float*)d_in[33];
    const float* lng = (const float*)d_in[34];
    const float* lnb = (const float*)d_in[35];
    const float* w1  = (const float*)d_in[36];
    const float* b1  = (const float*)d_in[37];
    const float* w2  = (const float*)d_in[38];
    const float* b2  = (const float*)d_in[39];
    const float* fcw = (const float*)d_in[40];
    const float* fcb = (const float*)d_in[41];
    const float* fng = (const float*)d_in[42];
    const float* fnb = (const float*)d_in[43];
    float* out = (float*)d_out;

    hipLaunchKernelGGL(mlp_head_kernel, dim3(256), dim3(512), 0, stream,
                       bio, wv, bv, wo, bo, lng, lnb,
                       w1, b1, w2, b2, fng, fnb, fcw, fcb, out);
}